// Round 1
// baseline (1241.933 us; speedup 1.0000x reference)
//
#include <hip/hip_runtime.h>
#include <hip/hip_bf16.h>

#define MOLC 128
#define HIDC 256
#define KTOT 384
#define TILE_N 128
#define NTHREADS 512
#define APAD 40   // f16 elems per LDS row (32 + 8 pad) -> 80B, breaks bank aliasing
#define WPAD 40

typedef _Float16 f16;
typedef _Float16 f16x8 __attribute__((ext_vector_type(8)));
typedef float    f32x4 __attribute__((ext_vector_type(4)));

__device__ inline f16x8 cvt8(float4 a, float4 b) {
  f16x8 r;
  r[0] = (f16)a.x; r[1] = (f16)a.y; r[2] = (f16)a.z; r[3] = (f16)a.w;
  r[4] = (f16)b.x; r[5] = (f16)b.y; r[6] = (f16)b.z; r[7] = (f16)b.w;
  return r;
}

__global__ void zero_out_kernel(float4* __restrict__ p, int n4) {
  int i = blockIdx.x * blockDim.x + threadIdx.x;
  if (i < n4) p[i] = make_float4(0.f, 0.f, 0.f, 0.f);
}

__global__ __launch_bounds__(NTHREADS, 2) void attn_pool_kernel(
    const float* __restrict__ input_rep,
    const float* __restrict__ final_rep,
    const int*   __restrict__ gidx,
    const float* __restrict__ W_lin,
    const float* __restrict__ b_lin,
    const float* __restrict__ W_last,
    const float* __restrict__ b_last,
    float* __restrict__ out,
    int n_nodes)
{
  __shared__ f16 A_lds[TILE_N * APAD];   // 10240 B
  __shared__ f16 W1_lds[HIDC * WPAD];    // 20480 B
  __shared__ f16 W2_lds[HIDC * WPAD];    // 20480 B
  __shared__ int gi_lds[TILE_N];         // 512 B

  const int t    = threadIdx.x;
  const int nb   = blockIdx.x * TILE_N;
  const int vn   = min(TILE_N, n_nodes - nb);

  const int lane = t & 63;
  const int w    = t >> 6;          // wave 0..7
  const int h    = w >> 2;          // node half (0/1): nodes [h*64, h*64+64)
  const int wch  = (w & 3) * 64;    // channel base for this wave
  const int lr   = lane & 15;
  const int lq   = lane >> 4;

  if (t < TILE_N) gi_lds[t] = (nb + t < n_nodes) ? gidx[nb + t] : -1;

  f32x4 acc1[4][4];
  f32x4 acc2[4][4];
#pragma unroll
  for (int i = 0; i < 4; ++i)
#pragma unroll
    for (int j = 0; j < 4; ++j) {
      acc1[i][j] = (f32x4)(0.f);
      acc2[i][j] = (f32x4)(0.f);
    }

  // staging assignments
  const int arow = t >> 2;         // 0..127 node row
  const int acol = (t & 3) * 8;    // 0/8/16/24
  const int wrow = t >> 1;         // 0..255 weight out-channel
  const int wcol = (t & 1) * 16;   // 0/16

  for (int ks = 0; ks < 12; ++ks) {
    const int k0 = ks * 32;

    // ---- stage A tile: 128 nodes x 32 k (f32 -> f16) ----
    {
      float4 x0, x1;
      if (arow < vn) {
        const float* src = (ks < 4)
            ? (input_rep + (size_t)(nb + arow) * MOLC + (k0 + acol))
            : (final_rep + (size_t)(nb + arow) * HIDC + (k0 - MOLC + acol));
        x0 = *(const float4*)src;
        x1 = *(const float4*)(src + 4);
      } else {
        x0 = make_float4(0.f, 0.f, 0.f, 0.f);
        x1 = x0;
      }
      *(f16x8*)&A_lds[arow * APAD + acol] = cvt8(x0, x1);
    }

    // ---- stage W1 tile: 256 ch x 32 k from W_lin (L2-resident) ----
    {
      const float* src = W_lin + (size_t)wrow * KTOT + (k0 + wcol);
      float4 a = ((const float4*)src)[0];
      float4 b = ((const float4*)src)[1];
      float4 c = ((const float4*)src)[2];
      float4 d = ((const float4*)src)[3];
      *(f16x8*)&W1_lds[wrow * WPAD + wcol]     = cvt8(a, b);
      *(f16x8*)&W1_lds[wrow * WPAD + wcol + 8] = cvt8(c, d);
    }

    // ---- stage W2 tile when in final_rep K-range ----
    if (ks >= 4) {
      const float* src = W_last + (size_t)wrow * HIDC + (k0 - MOLC + wcol);
      float4 a = ((const float4*)src)[0];
      float4 b = ((const float4*)src)[1];
      float4 c = ((const float4*)src)[2];
      float4 d = ((const float4*)src)[3];
      *(f16x8*)&W2_lds[wrow * WPAD + wcol]     = cvt8(a, b);
      *(f16x8*)&W2_lds[wrow * WPAD + wcol + 8] = cvt8(c, d);
    }

    __syncthreads();

    // ---- fragments + MFMA ----
    f16x8 af[4];
#pragma unroll
    for (int i = 0; i < 4; ++i)
      af[i] = *(const f16x8*)&A_lds[(h * 64 + i * 16 + lr) * APAD + lq * 8];

    {
      f16x8 bf[4];
#pragma unroll
      for (int j = 0; j < 4; ++j)
        bf[j] = *(const f16x8*)&W1_lds[(wch + j * 16 + lr) * WPAD + lq * 8];
#pragma unroll
      for (int i = 0; i < 4; ++i)
#pragma unroll
        for (int j = 0; j < 4; ++j)
          acc1[i][j] = __builtin_amdgcn_mfma_f32_16x16x32_f16(af[i], bf[j], acc1[i][j], 0, 0, 0);
    }
    if (ks >= 4) {
      f16x8 bf[4];
#pragma unroll
      for (int j = 0; j < 4; ++j)
        bf[j] = *(const f16x8*)&W2_lds[(wch + j * 16 + lr) * WPAD + lq * 8];
#pragma unroll
      for (int i = 0; i < 4; ++i)
#pragma unroll
        for (int j = 0; j < 4; ++j)
          acc2[i][j] = __builtin_amdgcn_mfma_f32_16x16x32_f16(af[i], bf[j], acc2[i][j], 0, 0, 0);
    }

    __syncthreads();
  }

  // ---- epilogue: g = sigmoid(acc1 + b_lin) * (acc2 + b_last) ----
  float bl[4], bb[4];
#pragma unroll
  for (int j = 0; j < 4; ++j) {
    bl[j] = b_lin[wch + j * 16 + lr];
    bb[j] = b_last[wch + j * 16 + lr];
  }
#pragma unroll
  for (int i = 0; i < 4; ++i)
#pragma unroll
    for (int j = 0; j < 4; ++j)
#pragma unroll
      for (int r = 0; r < 4; ++r) {
        float a   = acc1[i][j][r] + bl[j];
        float att = 1.f / (1.f + __expf(-a));
        acc1[i][j][r] = att * (acc2[i][j][r] + bb[j]);
      }

  // ---- scatter: segment-sum over sorted graph ids, then atomicAdd ----
  // C/D mapping: node = nb + h*64 + i*16 + lq*4 + r ; ch = wch + j*16 + lr
  for (int i = 0; i < 4; ++i) {
    const int base = h * 64 + i * 16;
    int myg[4];
#pragma unroll
    for (int r = 0; r < 4; ++r) myg[r] = gi_lds[base + lq * 4 + r];

    int s = 0;
    while (s < 16) {
      const int gid = gi_lds[base + s];
      int e = s + 1;
      while (e < 16 && gi_lds[base + e] == gid) ++e;
      if (gid >= 0) {
#pragma unroll
        for (int j = 0; j < 4; ++j) {
          float v = 0.f;
#pragma unroll
          for (int r = 0; r < 4; ++r)
            if (myg[r] == gid) v += acc1[i][j][r];
          v += __shfl_xor(v, 16);
          v += __shfl_xor(v, 32);
          if (lane < 16)
            atomicAdd(&out[(size_t)gid * HIDC + wch + j * 16 + lane], v);
        }
      }
      s = e;
    }
  }
}

extern "C" void kernel_launch(void* const* d_in, const int* in_sizes, int n_in,
                              void* d_out, int out_size, void* d_ws, size_t ws_size,
                              hipStream_t stream) {
  const float* input_rep = (const float*)d_in[0];
  const float* final_rep = (const float*)d_in[1];
  const int*   gidx      = (const int*)d_in[2];
  const float* W_lin     = (const float*)d_in[3];
  const float* b_lin     = (const float*)d_in[4];
  const float* W_last    = (const float*)d_in[5];
  const float* b_last    = (const float*)d_in[6];
  float* out = (float*)d_out;

  const int n_nodes = in_sizes[0] / MOLC;

  // zero-init output (harness poisons it with 0xAA before every launch)
  const int n4 = out_size / 4;
  zero_out_kernel<<<(n4 + 255) / 256, 256, 0, stream>>>((float4*)out, n4);

  const int grid = (n_nodes + TILE_N - 1) / TILE_N;
  attn_pool_kernel<<<grid, NTHREADS, 0, stream>>>(
      input_rep, final_rep, gidx, W_lin, b_lin, W_last, b_last, out, n_nodes);
}

// Round 3
// 1021.886 us; speedup vs baseline: 1.2153x; 1.2153x over previous
//
#include <hip/hip_runtime.h>
#include <hip/hip_bf16.h>

// Round 3 (= round 2 resubmitted; infra timeout, never ran): latency-bound fix.
//  - weights pre-packed to f16 (pre-swizzled) in d_ws; staged via global_load_lds
//  - double-buffered LDS, 1 barrier per K-step, prefetch next step during MFMA
//  - 256-thr blocks, TILE_N=64, 72.25KB LDS -> 2 blocks/CU for cross-block overlap
//  - XOR swizzle (slot ^ (row^(row>>2))&3) on A and W tiles: 8 touches/bank = HW minimum

#define MOLC 128
#define HIDC 256
#define KTOT 384
#define NKT  12        // K tiles of 32
#define TILE_N 64
#define NTHREADS 256

typedef _Float16 f16;
typedef _Float16 f16x8 __attribute__((ext_vector_type(8)));
typedef float    f32x4 __attribute__((ext_vector_type(4)));

__device__ __host__ __forceinline__ int swz(int r) { return (r ^ (r >> 2)) & 3; }

__device__ __forceinline__ f16x8 cvt8(float4 a, float4 b) {
  f16x8 r;
  r[0] = (f16)a.x; r[1] = (f16)a.y; r[2] = (f16)a.z; r[3] = (f16)a.w;
  r[4] = (f16)b.x; r[5] = (f16)b.y; r[6] = (f16)b.z; r[7] = (f16)b.w;
  return r;
}

#define GLL16(g, l) __builtin_amdgcn_global_load_lds(                          \
    (const __attribute__((address_space(1))) uint32_t*)(g),                    \
    (__attribute__((address_space(3))) uint32_t*)(l), 16, 0, 0)

__global__ void zero_out_kernel(float4* __restrict__ p, int n4) {
  int i = blockIdx.x * blockDim.x + threadIdx.x;
  if (i < n4) p[i] = make_float4(0.f, 0.f, 0.f, 0.f);
}

// Pack W_lin/W_last -> f16 tiles in d_ws, pre-swizzled so that a LINEAR
// global_load_lds write produces the swizzled LDS layout the reads expect.
// W1: 12 tiles x [256 rows x 4 slots x 8 f16] ; W2: 8 tiles, offset 98304 elems.
__global__ void pack_weights_kernel(const float* __restrict__ W_lin,
                                    const float* __restrict__ W_last,
                                    f16* __restrict__ ws) {
  int s = blockIdx.x * blockDim.x + threadIdx.x;
  if (s >= 20480) return;
  const float* src;
  f16* dst;
  if (s < 12288) {
    int ks = s >> 10, r = (s >> 2) & 255, c = s & 3;
    src = W_lin + (size_t)r * KTOT + ks * 32 + ((c ^ swz(r)) * 8);
    dst = ws + (size_t)s * 8;
  } else {
    int s2 = s - 12288;
    int ks = s2 >> 10, r = (s2 >> 2) & 255, c = s2 & 3;
    src = W_last + (size_t)r * HIDC + ks * 32 + ((c ^ swz(r)) * 8);
    dst = ws + 98304 + (size_t)s2 * 8;
  }
  f16x8 v;
#pragma unroll
  for (int j = 0; j < 8; ++j) v[j] = (f16)src[j];
  *(f16x8*)dst = v;
}

// stage one 16KB weight tile: 16 chunks of 1KB; 4 waves take 4 chunks each
__device__ __forceinline__ void stage_w(const f16* gtile, f16* ltile, int wv, int lane) {
#pragma unroll
  for (int c = 0; c < 4; ++c) {
    const int off = (wv * 4 + c) * 1024 + lane * 16;   // bytes
    GLL16((const char*)gtile + off, (char*)ltile + off);
  }
}

__global__ __launch_bounds__(NTHREADS, 2) void attn_pool_kernel(
    const float* __restrict__ input_rep,
    const float* __restrict__ final_rep,
    const int*   __restrict__ gidx,
    const f16*   __restrict__ ws,      // packed weights
    const float* __restrict__ b_lin,
    const float* __restrict__ b_last,
    float* __restrict__ out,
    int n_nodes)
{
  __shared__ f16 Abuf[2][TILE_N * 32];   // 4KB x2
  __shared__ f16 W1buf[2][HIDC * 32];    // 16KB x2
  __shared__ f16 W2buf[2][HIDC * 32];    // 16KB x2
  __shared__ int gi[TILE_N];

  const int t    = threadIdx.x;
  const int nb   = blockIdx.x * TILE_N;
  const int vn   = min(TILE_N, n_nodes - nb);
  const int lane = t & 63;
  const int wv   = t >> 6;          // wave 0..3
  const int wch  = wv * 64;         // channel base of this wave
  const int lr   = lane & 15;
  const int lq   = lane >> 4;
  const int sl   = (lq ^ swz(lr)) * 8;   // swizzled slot (f16 elems) for frag reads

  const int arow  = t >> 2;         // 0..63
  const int aslot = t & 3;
  const int awslot = (aslot ^ swz(arow)) * 8;

  if (t < TILE_N) gi[t] = (nb + t < n_nodes) ? gidx[nb + t] : -1;

  const f16* wsW1 = ws;             // tile ks at +ks*8192 elems
  const f16* wsW2 = ws + 98304;     // tile ks at +(ks-4)*8192 elems

  // ---- prologue: stage tile 0 ----
  stage_w(wsW1, W1buf[0], wv, lane);
  {
    float4 x0, x1;
    if (arow < vn) {
      const float* src = input_rep + (size_t)(nb + arow) * MOLC + aslot * 8;
      x0 = ((const float4*)src)[0];
      x1 = ((const float4*)src)[1];
    } else {
      x0 = make_float4(0.f, 0.f, 0.f, 0.f); x1 = x0;
    }
    *(f16x8*)&Abuf[0][arow * 32 + awslot] = cvt8(x0, x1);
  }
  __syncthreads();   // drains vmcnt (gload_lds) + lgkmcnt

  f32x4 acc1[4][4], acc2[4][4];
#pragma unroll
  for (int i = 0; i < 4; ++i)
#pragma unroll
    for (int j = 0; j < 4; ++j) { acc1[i][j] = (f32x4)(0.f); acc2[i][j] = (f32x4)(0.f); }

  for (int ks = 0; ks < NKT; ++ks) {
    const int cur = ks & 1, nxt = cur ^ 1;
    const int kn  = ks + 1;
    const bool pf = (kn < NKT);

    // ---- issue next-step staging first (async; latency hidden under MFMA) ----
    float4 x0, x1;
    if (pf) {
      stage_w(wsW1 + kn * 8192, W1buf[nxt], wv, lane);
      if (kn >= 4) stage_w(wsW2 + (kn - 4) * 8192, W2buf[nxt], wv, lane);
      if (arow < vn) {
        const float* src = (kn < 4)
            ? input_rep + (size_t)(nb + arow) * MOLC + kn * 32 + aslot * 8
            : final_rep + (size_t)(nb + arow) * HIDC + (kn * 32 - MOLC) + aslot * 8;
        x0 = ((const float4*)src)[0];
        x1 = ((const float4*)src)[1];
      } else {
        x0 = make_float4(0.f, 0.f, 0.f, 0.f); x1 = x0;
      }
    }

    // ---- fragments from current buffers + MFMA ----
    f16x8 af[4];
#pragma unroll
    for (int i = 0; i < 4; ++i)
      af[i] = *(const f16x8*)&Abuf[cur][(i * 16 + lr) * 32 + sl];

    {
      f16x8 bf[4];
#pragma unroll
      for (int j = 0; j < 4; ++j)
        bf[j] = *(const f16x8*)&W1buf[cur][(wch + j * 16 + lr) * 32 + sl];
#pragma unroll
      for (int i = 0; i < 4; ++i)
#pragma unroll
        for (int j = 0; j < 4; ++j)
          acc1[i][j] = __builtin_amdgcn_mfma_f32_16x16x32_f16(af[i], bf[j], acc1[i][j], 0, 0, 0);
    }
    if (ks >= 4) {
      f16x8 bf[4];
#pragma unroll
      for (int j = 0; j < 4; ++j)
        bf[j] = *(const f16x8*)&W2buf[cur][(wch + j * 16 + lr) * 32 + sl];
#pragma unroll
      for (int i = 0; i < 4; ++i)
#pragma unroll
        for (int j = 0; j < 4; ++j)
          acc2[i][j] = __builtin_amdgcn_mfma_f32_16x16x32_f16(af[i], bf[j], acc2[i][j], 0, 0, 0);
    }

    // ---- late A write into next buffer ----
    if (pf) *(f16x8*)&Abuf[nxt][arow * 32 + awslot] = cvt8(x0, x1);

    __syncthreads();   // one barrier per K-step (drains gload_lds for next step)
  }

  // ---- epilogue: g = sigmoid(acc1 + b_lin) * (acc2 + b_last) ----
  float bl[4], bb[4];
#pragma unroll
  for (int j = 0; j < 4; ++j) {
    bl[j] = b_lin[wch + j * 16 + lr];
    bb[j] = b_last[wch + j * 16 + lr];
  }
#pragma unroll
  for (int i = 0; i < 4; ++i)
#pragma unroll
    for (int j = 0; j < 4; ++j)
#pragma unroll
      for (int r = 0; r < 4; ++r) {
        float a   = acc1[i][j][r] + bl[j];
        float att = 1.f / (1.f + __expf(-a));
        acc1[i][j][r] = att * (acc2[i][j][r] + bb[j]);
      }

  // ---- scatter: per-16-node segment scan (gidx sorted), then atomicAdd ----
  // C/D map: node = nb + i*16 + lq*4 + r ; ch = wch + j*16 + lr
  for (int i = 0; i < 4; ++i) {
    const int base = i * 16;
    int myg[4];
#pragma unroll
    for (int r = 0; r < 4; ++r) myg[r] = gi[base + lq * 4 + r];

    int s = 0;
    while (s < 16) {
      const int gid = gi[base + s];
      int e = s + 1;
      while (e < 16 && gi[base + e] == gid) ++e;
      if (gid >= 0) {
#pragma unroll
        for (int j = 0; j < 4; ++j) {
          float v = 0.f;
#pragma unroll
          for (int r = 0; r < 4; ++r)
            if (myg[r] == gid) v += acc1[i][j][r];
          v += __shfl_xor(v, 16);
          v += __shfl_xor(v, 32);
          if (lane < 16)
            atomicAdd(&out[(size_t)gid * HIDC + wch + j * 16 + lane], v);
        }
      }
      s = e;
    }
  }
}

extern "C" void kernel_launch(void* const* d_in, const int* in_sizes, int n_in,
                              void* d_out, int out_size, void* d_ws, size_t ws_size,
                              hipStream_t stream) {
  const float* input_rep = (const float*)d_in[0];
  const float* final_rep = (const float*)d_in[1];
  const int*   gidx      = (const int*)d_in[2];
  const float* W_lin     = (const float*)d_in[3];
  const float* b_lin     = (const float*)d_in[4];
  const float* W_last    = (const float*)d_in[5];
  const float* b_last    = (const float*)d_in[6];
  float* out = (float*)d_out;
  f16*   ws  = (f16*)d_ws;

  const int n_nodes = in_sizes[0] / MOLC;

  const int n4 = out_size / 4;
  zero_out_kernel<<<(n4 + 255) / 256, 256, 0, stream>>>((float4*)out, n4);

  pack_weights_kernel<<<80, 256, 0, stream>>>(W_lin, W_last, ws);

  const int grid = (n_nodes + TILE_N - 1) / TILE_N;
  attn_pool_kernel<<<grid, NTHREADS, 0, stream>>>(
      input_rep, final_rep, gidx, ws, b_lin, b_last, out, n_nodes);
}